// Round 14
// baseline (48.751 us; speedup 1.0000x reference)
//
#include <hip/hip_runtime.h>

typedef _Float16 half8 __attribute__((ext_vector_type(8)));
typedef float f32x16 __attribute__((ext_vector_type(16)));

#define SLOT 27648                 // 27 frags * 1KB
#define LDS_TOTAL (2 * SLOT)       // 55296 B (B double-buffer only)
#define PX_OFF 450560              // packed-x offset in d_ws (after B frags+bias)

// async global->LDS, 16B/lane; dest is the WAVE-UNIFORM base (HW adds lane*16)
__device__ __forceinline__ void stage16(const void* g, const void* l) {
  __builtin_amdgcn_global_load_lds(
      (const __attribute__((address_space(1))) unsigned int*)(unsigned long long)g,
      (__attribute__((address_space(3))) unsigned int*)(unsigned int)(unsigned long long)l,
      16, 0, 0);
}

// ---------------------------------------------------------------------------
// Pre-pack W [55,64,64] f32 -> f16 MFMA B-fragments, order [nt][set][l]:
// set = ks*2+cc; frag f = (nt*4+set)*54 + l ; elem e = lane*8 + v ;
// value = W[l, set*16 + (lane>>5)*8 + v, nt*32 + (lane&31)].
// Bias row (l=54) folded to f32[64] at byte offset 442368.
// ---------------------------------------------------------------------------
__global__ __launch_bounds__(256)
void prepack_kernel(const float* __restrict__ W, _Float16* __restrict__ Bp) {
  const int idx = blockIdx.x * 256 + threadIdx.x;
  if (idx < 221184) {                    // 432 frags * 512 elems
    const int v   = idx & 7;
    const int lam = (idx >> 3) & 63;
    const int f   = idx >> 9;
    const int l   = f % 54;
    const int r   = f / 54;              // nt*4 + set
    const int set = r & 3;
    const int nt  = r >> 2;
    const int c   = set * 16 + (lam >> 5) * 8 + v;
    const int o   = nt * 32 + (lam & 31);
    Bp[idx] = (_Float16)W[(l * 64 + c) * 64 + o];
  } else if (idx < 221184 + 64) {
    const int o = idx - 221184;
    float s = 0.f;
    for (int c = 0; c < 64; ++c) s += W[(54 * 64 + c) * 64 + o];
    ((float*)(Bp + 221184))[o] = s;
  }
}

// ---------------------------------------------------------------------------
// Pack x [16,64,64,64] f32 -> f16 px[b][set][kg][row][col 0..65][8ch],
// halo cols 0 and 65 zeroed. Tap reads become coalesced 16B/lane loads.
// ---------------------------------------------------------------------------
__global__ __launch_bounds__(256)
void xpack_kernel(const float* __restrict__ x, _Float16* __restrict__ px) {
  const int idx = blockIdx.x * 256 + threadIdx.x;
  if (idx >= 16 * 64 * 64 * 8) return;
  const int ch8 = idx & 7;                 // set = ch8>>1, kg = ch8&1
  const int col = (idx >> 3) & 63;
  const int row = (idx >> 9) & 63;
  const int b   = idx >> 15;
  const float* src = x + ((((size_t)b * 64 + row) * 64 + col) * 64) + ch8 * 8;
  const float4 v0 = *(const float4*)src;
  const float4 v1 = *(const float4*)(src + 4);
  half8 h;
  h[0] = (_Float16)v0.x; h[1] = (_Float16)v0.y;
  h[2] = (_Float16)v0.z; h[3] = (_Float16)v0.w;
  h[4] = (_Float16)v1.x; h[5] = (_Float16)v1.y;
  h[6] = (_Float16)v1.z; h[7] = (_Float16)v1.w;
  const size_t base = (((size_t)b * 8 + ch8) * 64 + row) * 66;  // row of 66 cols
  *(half8*)(px + (base + col + 1) * 8) = h;
  if (col == 0) {
    half8 z = {};
    *(half8*)(px + (base + 0) * 8)  = z;
    *(half8*)(px + (base + 65) * 8) = z;
  }
}

// ---------------------------------------------------------------------------
// Block = 256 thr = 4 waves = 4 image rows x one nt; wave = 1 row: M=64
// (2 m-tiles of 32), N=32. Grid 512 = 2 blocks/CU (8 waves/CU, 2/SIMD).
// 8 rounds of 27 l (set = ks*2+cc changes every 2 rounds). B double-buffered
// 2x27KB: round r = { issue stage(r+1); compute(r); vmcnt(0); barrier } ->
// staging has the whole round to land (true overlap). Taps read directly
// from packed-x in global/L2 (coalesced 16B/lane) - LDS holds ONLY B.
// ---------------------------------------------------------------------------
__global__ __launch_bounds__(256, 2)
void qconv_kernel(const _Float16* __restrict__ Bp, float* __restrict__ out) {
  constexpr int IU[45] = {0,0,0,0,0,0,0,0,0, 1,1,1,1,1,1,1,1, 2,2,2,2,2,2,2,
                          3,3,3,3,3,3, 4,4,4,4,4, 5,5,5,5, 6,6,6, 7,7, 8};
  constexpr int JU[45] = {0,1,2,3,4,5,6,7,8, 1,2,3,4,5,6,7,8, 2,3,4,5,6,7,8,
                          3,4,5,6,7,8, 4,5,6,7,8, 5,6,7,8, 6,7,8, 7,8, 8};

  const int tid  = threadIdx.x;
  const int wave = tid >> 6;               // 0..3 -> image row r0+wave
  const int lane = tid & 63;
  const int colA = lane & 31;
  const int kg   = lane >> 5;

  // XCD-aware bijective remap (512 % 8 == 0): 64 blocks/XCD -> 2 images
  const int phys = blockIdx.x;
  const int logical = (phys & 7) * 64 + (phys >> 3);
  const int nt  = logical & 1;
  const int grp = logical >> 1;            // 0..255
  const int b   = grp >> 4;
  const int r0  = (grp & 15) * 4;
  const int r   = r0 + wave;               // this wave's image row

  __shared__ __align__(16) unsigned char smem[LDS_TOTAL];
  const char* BpB = (const char*)Bp;
  const _Float16* px = (const _Float16*)(BpB + PX_OFF);

  f32x16 acc[2] = {};
  half8 tapA[2][9], tapB[2][9];            // 144 VGPRs (two tap sets)
  half8 bqE[9], bqO[9];                    // 72 VGPRs

#define TAPG(TP, SET)                                                       \
  _Pragma("unroll")                                                         \
  for (int t = 0; t < 9; ++t) {                                             \
    const int rr = r + t / 3 - 1;                                           \
    const bool ok = ((unsigned)rr < 64u);                                   \
    _Pragma("unroll")                                                       \
    for (int mt = 0; mt < 2; ++mt) {                                        \
      half8 tv = {};                                                        \
      if (ok)                                                               \
        tv = *(const half8*)(px + ((((size_t)b * 8 + (SET) * 2 + kg) * 64   \
              + rr) * 66 + (mt * 32 + colA + t % 3)) * 8);                  \
      TP[mt][t] = tv;                                                       \
    }                                                                       \
  }

#define LOADQ9(BUFQ, BUF, PH)                                               \
  _Pragma("unroll")                                                         \
  for (int q = 0; q < 9; ++q)                                               \
    BUFQ[q] = *(const half8*)(smem + (BUF) * SLOT + ((PH) * 9 + q) * 1024   \
                              + lane * 16);

#define WAITSB(n)                                                           \
  asm volatile("s_waitcnt lgkmcnt(" #n ")" ::: "memory");                   \
  __builtin_amdgcn_sched_barrier(0);

#define MFMA9(TP, BUFQ, L0)                                                 \
  __builtin_amdgcn_s_setprio(1);                                            \
  _Pragma("unroll")                                                         \
  for (int q = 0; q < 9; ++q) {                                             \
    const int l = (L0) + q;                                                 \
    half8 a0, a1;                                                           \
    if (l < 45) { a0 = TP[0][IU[l]] * TP[0][JU[l]];                         \
                  a1 = TP[1][IU[l]] * TP[1][JU[l]]; }                       \
    else        { a0 = TP[0][l - 45]; a1 = TP[1][l - 45]; }                 \
    acc[0] = __builtin_amdgcn_mfma_f32_32x32x16_f16(a0, BUFQ[q], acc[0],    \
                                                    0, 0, 0);               \
    acc[1] = __builtin_amdgcn_mfma_f32_32x32x16_f16(a1, BUFQ[q], acc[1],    \
                                                    0, 0, 0);               \
  }                                                                         \
  __builtin_amdgcn_s_setprio(0);

// Round: BUF = this round's buffer (static), NBUF = 1-BUF, LH = l-half (0/1),
// TP = tap set, DOSTG = stage next round?, SBN/LHN = next round's B source.
#define ROUND(BUF, NBUF, LH, TP, DOSTG, SBN, LHN)                           \
  {                                                                         \
    if (DOSTG)                                                              \
      for (int f = wave; f < 27; f += 4)                                    \
        stage16(BpB + (SBN) + (size_t)((LHN) * 27 + f) * 1024 + lane * 16,  \
                (char*)smem + (NBUF) * SLOT + f * 1024);                    \
    LOADQ9(bqE, BUF, 0);                                                    \
    LOADQ9(bqO, BUF, 1);  WAITSB(9);  MFMA9(TP, bqE, (LH) * 27 + 0);        \
    LOADQ9(bqE, BUF, 2);  WAITSB(9);  MFMA9(TP, bqO, (LH) * 27 + 9);        \
                          WAITSB(0);  MFMA9(TP, bqE, (LH) * 27 + 18);       \
    asm volatile("s_waitcnt vmcnt(0)" ::: "memory");                        \
    __syncthreads();                                                        \
  }

  // ---- prologue: stage round 0 (set 0, lh 0) into buf0 -------------------
  {
    const size_t sb = (size_t)(nt * 4) * 55296;
    for (int f = wave; f < 27; f += 4)
      stage16(BpB + sb + (size_t)f * 1024 + lane * 16,
              (char*)smem + f * 1024);
    asm volatile("s_waitcnt vmcnt(0)" ::: "memory");
    __syncthreads();
  }

  for (int su = 0; su < 2; ++su) {         // sets 2su (tapA), 2su+1 (tapB)
    const size_t sb0 = (size_t)(nt * 4 + su * 2) * 55296;
    const size_t sb1 = sb0 + 55296;
    const size_t sb2 = sb1 + 55296;        // next su's first set (su=0 only)
    TAPG(tapA, su * 2);
    ROUND(0, 1, 0, tapA, 1,         sb0, 1);
    ROUND(1, 0, 1, tapA, 1,         sb1, 0);
    TAPG(tapB, su * 2 + 1);
    ROUND(0, 1, 0, tapB, 1,         sb1, 1);
    ROUND(1, 0, 1, tapB, (su == 0), sb2, 0);
  }

  // ---- epilogue: bias + coalesced stores ---------------------------------
  const float bias = ((const float*)(BpB + 442368))[nt * 32 + colA];
#pragma unroll
  for (int mt = 0; mt < 2; ++mt) {
    float* op = out + (((size_t)b * 64 + r) * 64 + mt * 32) * 64
                    + nt * 32 + colA;
#pragma unroll
    for (int gi = 0; gi < 16; ++gi) {
      const int rowD = (gi & 3) + 8 * (gi >> 2) + 4 * kg;  // pixel within mt
      op[(size_t)rowD * 64] = acc[mt][gi] + bias;
    }
  }
}

extern "C" void kernel_launch(void* const* d_in, const int* in_sizes, int n_in,
                              void* d_out, int out_size, void* d_ws, size_t ws_size,
                              hipStream_t stream) {
  const float* x = (const float*)d_in[0];
  const float* W = (const float*)d_in[1];
  float* out     = (float*)d_out;
  _Float16* Bp   = (_Float16*)d_ws;                       // B frags + bias
  _Float16* px   = (_Float16*)((char*)d_ws + PX_OFF);     // packed x (8.65 MB)

  prepack_kernel<<<dim3((221248 + 255) / 256), dim3(256), 0, stream>>>(W, Bp);
  xpack_kernel<<<dim3(2048), dim3(256), 0, stream>>>(x, px);
  qconv_kernel<<<dim3(512), dim3(256), 0, stream>>>(Bp, out);
}